// Round 1
// baseline (436.608 us; speedup 1.0000x reference)
//
#include <hip/hip_runtime.h>
#include <hip/hip_fp16.h>

// Problem dims (fixed by reference)
#define S_LEN 1024
#define BSZ   32
#define IN_DIM 1024
#define HID   1024
#define MDIM  (S_LEN*BSZ)   // 32768 GEMM rows
#define NDIM  (2*HID)       // 2048 GEMM cols (z | f interleaved in 16-row groups)
#define KDIM  IN_DIM        // 1024

typedef __attribute__((ext_vector_type(8))) _Float16 half8;
typedef __attribute__((ext_vector_type(2))) _Float16 half2v;
typedef __attribute__((ext_vector_type(4))) float    floatx4;

// ---------------- fp32 -> fp16 conversion ----------------
__global__ void cvt_x_kernel(const float* __restrict__ x, _Float16* __restrict__ xh) {
    int idx = blockIdx.x * blockDim.x + threadIdx.x;   // one half8 (8 elems) per thread
    const float4* src = (const float4*)x + (size_t)idx * 2;
    float4 a = src[0], b = src[1];
    half8 h;
    h[0] = (_Float16)a.x; h[1] = (_Float16)a.y; h[2] = (_Float16)a.z; h[3] = (_Float16)a.w;
    h[4] = (_Float16)b.x; h[5] = (_Float16)b.y; h[6] = (_Float16)b.z; h[7] = (_Float16)b.w;
    *((half8*)xh + idx) = h;
}

// Interleaved weight layout: out row r (0..2047): g=r>>5, sub=r&31.
// sub<16 -> wm_z row g*16+sub ; sub>=16 -> wm_f row g*16+(sub-16).
__global__ void cvt_w_kernel(const float* __restrict__ wz, const float* __restrict__ wf,
                             _Float16* __restrict__ wh) {
    int idx = blockIdx.x * blockDim.x + threadIdx.x;   // one half8 per thread
    int e0 = idx * 8;
    int r   = e0 >> 10;        // output row 0..2047
    int col = e0 & 1023;
    int g = r >> 5, sub = r & 31;
    const float* src = (sub < 16)
        ? wz + ((size_t)(g * 16 + sub)      * KDIM + col)
        : wf + ((size_t)(g * 16 + sub - 16) * KDIM + col);
    const float4* s4 = (const float4*)src;
    float4 a = s4[0], b = s4[1];
    half8 h;
    h[0] = (_Float16)a.x; h[1] = (_Float16)a.y; h[2] = (_Float16)a.z; h[3] = (_Float16)a.w;
    h[4] = (_Float16)b.x; h[5] = (_Float16)b.y; h[6] = (_Float16)b.z; h[7] = (_Float16)b.w;
    *((half8*)wh + idx) = h;
}

// ---------------- fp16 MFMA GEMM, 256x256 8-phase schedule ----------------
// BM=BN=256, BK=64, 8 waves (2M x 4N), LDS 128KB = 2 bufs x (A 32KB + B 32KB).
// Per K-tile per wave: 64 MFMA (8 m-frags x 4 n-frags x 2 k-steps), split into
// 4 phases of 16 MFMA (2 m-frag-rows each). Iteration = 2 K-tiles = 8 phases.
//
// LDS swizzle (T2): byte kb within a 128B row is XORed with (row&7)<<4 on BOTH
// sides — ds_read address, and pre-applied to the per-lane GLOBAL source of
// global_load_lds (LDS dest stays linear; rule #21). Spreads a 16-row b128
// column read evenly over all 32 banks.
//
// Stage schedule (hazard ledger: each staged region's last ds_read is >=1 phase
// earlier; barriers between phases make write-after-read safe):
//   ph0: A13(buf1, t+1)   (A1/A3 of buf1 last read in prev ph6/ph7)
//   ph1: B01(buf0, t+2)   (B(buf0) fully consumed in ph0)
//   ph2: A02(buf0, t+2)   (A0/A2 consumed by end ph1)
//   ph3: B23(buf0, t+2)
//   ph4: A13(buf0, t+2)   (A1/A3 consumed by end ph3)
//   ph5: B01(buf1, t+3)   (B(buf1) consumed in ph4)
//   ph6: A02(buf1, t+3)
//   ph7: B23(buf1, t+3)
// Waits (T4, per-wave vmcnt + barrier => all waves' shares landed):
//   end ph3: vmcnt(6) -> everything through ph0 landed = buf1(t+1) complete
//            (last iteration: only ph0's 2 loads outstanding -> vmcnt(0))
//   end ph7: vmcnt(6) -> everything through ph4 landed = buf0(t+2) complete
#define BM 256
#define BN 256
#define BK 64
#define NKT (KDIM / BK)   // 16 K-tiles
#define NIT (NKT / 2)     // 8 iterations

__global__ __launch_bounds__(512, 2) void gemm_f16_kernel(
    const _Float16* __restrict__ A, const _Float16* __restrict__ B,
    uint* __restrict__ zf) {
    __shared__ __attribute__((aligned(128))) _Float16 smem[65536];  // 128 KB
    char* smb = (char*)smem;

    const int tid  = threadIdx.x;
    const int lane = tid & 63;
    const int wv   = tid >> 6;               // wave 0..7
    const int wm_off = (wv >> 2) * 128;      // wave's 128-row A half
    const int wn_off = (wv & 3) * 64;        // wave's 64-row B quarter

    // grid 1024 = 128 m-tiles x 8 n-tiles; XCD-aware swizzle (nwg%8==0, bijective)
    const int flat   = blockIdx.x;
    const int xcd    = flat & 7;
    const int local  = flat >> 3;                 // 0..127
    const int tile_m = (local >> 3) * 8 + xcd;    // 0..127
    const int tile_n = local & 7;                 // 0..7, fastest -> A-panel L2 reuse
    const int m0  = tile_m * BM;
    const int n0g = tile_n * BN;

    const int fr  = lane & 15;               // fragment row within 16
    const int fkb = (lane >> 4) * 16;        // fragment k-chunk byte offset (0..48)

    // staging lane constants: lane covers LDS linear bytes (lane*16) of an 8-row slice;
    // source k-byte is pre-swizzled: ((lane&7)^(lane>>3))<<4
    const int srow = lane >> 3;                       // 0..7
    const int skb  = ((lane & 7) ^ srow) << 4;        // pre-swizzled global k-byte

    floatx4 acc[8][4] = {};

    // STAGE one 8KB sub-chunk: 64 rows (R0..R0+63) x 64 k of one matrix into LDS.
    // regionBase: A(buf)=buf*65536, B(buf)=buf*65536+32768. 1 load/thread.
    auto STAGE = [&](const _Float16* __restrict__ src, int gRow0, int regionBase,
                     int R0, int kt) {
        int r = R0 + wv * 8 + srow;
        const _Float16* gp = src + (size_t)(gRow0 + r) * KDIM + kt * BK + (skb >> 1);
        __builtin_amdgcn_global_load_lds(
            (const __attribute__((address_space(1))) void*)gp,
            (__attribute__((address_space(3))) void*)(smb + regionBase + (R0 + wv * 8) * 128),
            16, 0, 0);
    };
    // swizzled ds_read_b128 of fragment at (row r, k-byte kb) from region base rb
    auto LD8 = [&](int rb, int r, int kb) -> half8 {
        return *(const half8*)(smb + rb + r * 128 + (kb ^ ((r & 7) << 4)));
    };

    // ---- prologue: buf0 = tile0 (4 half-tiles), buf1 = tile1 (first 3) ----
    STAGE(B, n0g, 32768, 0, 0);           STAGE(B, n0g, 32768, 64, 0);
    STAGE(A, m0, 0, 0, 0);                STAGE(A, m0, 0, 128, 0);
    STAGE(B, n0g, 32768, 128, 0);         STAGE(B, n0g, 32768, 192, 0);
    STAGE(A, m0, 0, 64, 0);               STAGE(A, m0, 0, 192, 0);
    STAGE(B, n0g, 65536 + 32768, 0, 1);   STAGE(B, n0g, 65536 + 32768, 64, 1);
    STAGE(A, m0, 65536, 0, 1);            STAGE(A, m0, 65536, 128, 1);
    STAGE(B, n0g, 65536 + 32768, 128, 1); STAGE(B, n0g, 65536 + 32768, 192, 1);
    asm volatile("s_waitcnt vmcnt(6)" ::: "memory");  // oldest 8 = all of buf0 landed
    __builtin_amdgcn_s_barrier();
    asm volatile("" ::: "memory");

    half8 bfr[4][2];
    for (int it = 0; it < NIT; ++it) {
        const int  t    = 2 * it;
        const bool more = (it < NIT - 1);
        #pragma unroll
        for (int ph = 0; ph < 8; ++ph) {
            const int bb    = ph >> 2;           // buffer
            const int p     = ph & 3;            // sub-phase within K-tile
            const int bbase = bb * 65536;

            // ds-read register subtile (B cached across the 4 phases of a K-tile)
            if (p == 0) {
                #pragma unroll
                for (int j = 0; j < 4; ++j)
                    #pragma unroll
                    for (int ks = 0; ks < 2; ++ks) {
                        int r = wn_off + j * 16 + fr;
                        bfr[j][ks] = LD8(bbase + 32768, r, ks * 64 + fkb);
                    }
            }
            half8 afr[2][2];
            #pragma unroll
            for (int ii = 0; ii < 2; ++ii)
                #pragma unroll
                for (int ks = 0; ks < 2; ++ks) {
                    int r = wm_off + (2 * p + ii) * 16 + fr;
                    afr[ii][ks] = LD8(bbase, r, ks * 64 + fkb);
                }

            // stage one half-tile (2 sub-chunks) per the ledger above
            if (ph == 0) {
                STAGE(A, m0, 65536, 64, t + 1);  STAGE(A, m0, 65536, 192, t + 1);
            } else if (more) {
                if      (ph == 1) { STAGE(B, n0g, 32768, 0, t + 2);          STAGE(B, n0g, 32768, 64, t + 2); }
                else if (ph == 2) { STAGE(A, m0, 0, 0, t + 2);               STAGE(A, m0, 0, 128, t + 2); }
                else if (ph == 3) { STAGE(B, n0g, 32768, 128, t + 2);        STAGE(B, n0g, 32768, 192, t + 2); }
                else if (ph == 4) { STAGE(A, m0, 0, 64, t + 2);              STAGE(A, m0, 0, 192, t + 2); }
                else if (ph == 5) { STAGE(B, n0g, 65536 + 32768, 0, t + 3);  STAGE(B, n0g, 65536 + 32768, 64, t + 3); }
                else if (ph == 6) { STAGE(A, m0, 65536, 0, t + 3);           STAGE(A, m0, 65536, 128, t + 3); }
                else              { STAGE(B, n0g, 65536 + 32768, 128, t + 3); STAGE(B, n0g, 65536 + 32768, 192, t + 3); }
            }

            __builtin_amdgcn_s_barrier();
            asm volatile("s_waitcnt lgkmcnt(0)" ::: "memory");
            __builtin_amdgcn_s_setprio(1);
            #pragma unroll
            for (int ks = 0; ks < 2; ++ks)
                #pragma unroll
                for (int ii = 0; ii < 2; ++ii)
                    #pragma unroll
                    for (int j = 0; j < 4; ++j)
                        acc[2 * p + ii][j] = __builtin_amdgcn_mfma_f32_16x16x32_f16(
                            afr[ii][ks], bfr[j][ks], acc[2 * p + ii][j], 0, 0, 0);
            __builtin_amdgcn_s_setprio(0);
            if (ph == 3) {
                if (more) asm volatile("s_waitcnt vmcnt(6)" ::: "memory");
                else      asm volatile("s_waitcnt vmcnt(0)" ::: "memory");  // only ph0's 2 loads outstanding
            } else if (ph == 7) {
                if (more) asm volatile("s_waitcnt vmcnt(6)" ::: "memory");
            }
            __builtin_amdgcn_s_barrier();
            asm volatile("" ::: "memory");
        }
    }

    // epilogue: C/D layout col=lane&15, row=(lane>>4)*4+reg  [measured m89/m91]
    // col-tile pair (2p,2p+1) = (z,f) for h = ((n0g+wn_off)>>5 + p)*16 + ocol
    const int orow = (lane >> 4) * 4;
    const int ocol = lane & 15;
    const int gb   = (n0g + wn_off) >> 5;
    #pragma unroll
    for (int i = 0; i < 8; ++i)
        #pragma unroll
        for (int p2 = 0; p2 < 2; ++p2) {
            int hh = (gb + p2) * 16 + ocol;
            #pragma unroll
            for (int r = 0; r < 4; ++r) {
                int row = m0 + wm_off + i * 16 + orow + r;
                half2v v;
                v[0] = (_Float16)acc[i][2 * p2][r];       // z
                v[1] = (_Float16)acc[i][2 * p2 + 1][r];   // f
                *(half2v*)(zf + (size_t)row * HID + hh) = v;
            }
        }
}

// ---------------- sequential scan over s, one thread per (b,h) ----------------
#define UNR 32
__global__ __launch_bounds__(64) void scan_kernel(
    const uint* __restrict__ zf, float* __restrict__ out,
    const float* __restrict__ state,
    const float* __restrict__ wvz, const float* __restrict__ wvf,
    const float* __restrict__ bz, const float* __restrict__ bfv) {
    const int t = blockIdx.x * 64 + threadIdx.x;   // 0..32767
    const int h = t & (HID - 1);
    const int stride = BSZ * HID;                  // 32768 elements between timesteps

    float cell = state[t];
    const float az = wvz[h], afc = wvf[h], cz = bz[h], cf = bfv[h];

    const uint* p = zf + t;
    float* po = out + t;

    uint buf[UNR];
    #pragma unroll
    for (int u = 0; u < UNR; ++u) buf[u] = p[(size_t)u * stride];

    for (int s0 = 0; s0 < S_LEN; s0 += UNR) {
        uint nb[UNR];
        if (s0 + UNR < S_LEN) {
            #pragma unroll
            for (int u = 0; u < UNR; ++u)
                nb[u] = p[(size_t)(s0 + UNR + u) * stride];
        }
        #pragma unroll
        for (int u = 0; u < UNR; ++u) {
            half2v h2 = __builtin_bit_cast(half2v, buf[u]);
            float zpre = (float)h2[0] + az * cell + cz;
            float fpre = (float)h2[1] + afc * cell + cf;
            float ez = __expf(2.0f * zpre);
            float zp = (ez - 1.0f) * __builtin_amdgcn_rcpf(ez + 1.0f);
            float fp = __builtin_amdgcn_rcpf(1.0f + __expf(-fpre));
            cell = fmaf(cell - zp, fp, zp);        // cell*fp + (1-fp)*zp
            po[(size_t)(s0 + u) * stride] = cell;
        }
        #pragma unroll
        for (int u = 0; u < UNR; ++u) buf[u] = nb[u];
    }
}

extern "C" void kernel_launch(void* const* d_in, const int* in_sizes, int n_in,
                              void* d_out, int out_size, void* d_ws, size_t ws_size,
                              hipStream_t stream) {
    const float* x      = (const float*)d_in[0];
    const float* state  = (const float*)d_in[1];
    const float* wm_z   = (const float*)d_in[2];
    const float* wm_f   = (const float*)d_in[3];
    const float* wv_z   = (const float*)d_in[4];
    const float* wv_f   = (const float*)d_in[5];
    const float* bias_z = (const float*)d_in[6];
    const float* bias_f = (const float*)d_in[7];
    float* out = (float*)d_out;

    // workspace layout: xh 64MB | wh 4MB | zf 128MB  (total 196MB)
    char* ws = (char*)d_ws;
    _Float16* xh = (_Float16*)ws;
    _Float16* wh = (_Float16*)(ws + (size_t)MDIM * KDIM * sizeof(_Float16));
    uint* zf     = (uint*)(ws + (size_t)MDIM * KDIM * sizeof(_Float16)
                              + (size_t)NDIM * KDIM * sizeof(_Float16));

    // 1) convert inputs to fp16 (weights interleaved z|f in 16-row groups)
    cvt_x_kernel<<<(MDIM * KDIM) / (256 * 8), 256, 0, stream>>>(x, xh);
    cvt_w_kernel<<<(NDIM * KDIM) / (256 * 8), 256, 0, stream>>>(wm_z, wm_f, wh);

    // 2) fused z|f projection GEMM -> interleaved fp16 pre-activations
    gemm_f16_kernel<<<(MDIM / BM) * (NDIM / BN), 512, 0, stream>>>(xh, wh, zf);

    // 3) recurrence -> fp32 output
    scan_kernel<<<MDIM / 64, 64, 0, stream>>>(zf, out, state, wv_z, wv_f, bias_z, bias_f);
}

// Round 2
// 425.106 us; speedup vs baseline: 1.0271x; 1.0271x over previous
//
#include <hip/hip_runtime.h>
#include <hip/hip_fp16.h>

// Problem dims (fixed by reference)
#define S_LEN 1024
#define BSZ   32
#define IN_DIM 1024
#define HID   1024
#define MDIM  (S_LEN*BSZ)   // 32768 GEMM rows
#define NDIM  (2*HID)       // 2048 GEMM cols (z | f interleaved in 16-row groups)
#define KDIM  IN_DIM        // 1024

typedef __attribute__((ext_vector_type(8))) _Float16 half8;
typedef __attribute__((ext_vector_type(2))) _Float16 half2v;
typedef __attribute__((ext_vector_type(4))) float    floatx4;

// ---------------- fp32 -> fp16 conversion ----------------
__global__ void cvt_x_kernel(const float* __restrict__ x, _Float16* __restrict__ xh) {
    int idx = blockIdx.x * blockDim.x + threadIdx.x;   // one half8 (8 elems) per thread
    const float4* src = (const float4*)x + (size_t)idx * 2;
    float4 a = src[0], b = src[1];
    half8 h;
    h[0] = (_Float16)a.x; h[1] = (_Float16)a.y; h[2] = (_Float16)a.z; h[3] = (_Float16)a.w;
    h[4] = (_Float16)b.x; h[5] = (_Float16)b.y; h[6] = (_Float16)b.z; h[7] = (_Float16)b.w;
    *((half8*)xh + idx) = h;
}

// Interleaved weight layout: out row r (0..2047): g=r>>5, sub=r&31.
// sub<16 -> wm_z row g*16+sub ; sub>=16 -> wm_f row g*16+(sub-16).
__global__ void cvt_w_kernel(const float* __restrict__ wz, const float* __restrict__ wf,
                             _Float16* __restrict__ wh) {
    int idx = blockIdx.x * blockDim.x + threadIdx.x;   // one half8 per thread
    int e0 = idx * 8;
    int r   = e0 >> 10;        // output row 0..2047
    int col = e0 & 1023;
    int g = r >> 5, sub = r & 31;
    const float* src = (sub < 16)
        ? wz + ((size_t)(g * 16 + sub)      * KDIM + col)
        : wf + ((size_t)(g * 16 + sub - 16) * KDIM + col);
    const float4* s4 = (const float4*)src;
    float4 a = s4[0], b = s4[1];
    half8 h;
    h[0] = (_Float16)a.x; h[1] = (_Float16)a.y; h[2] = (_Float16)a.z; h[3] = (_Float16)a.w;
    h[4] = (_Float16)b.x; h[5] = (_Float16)b.y; h[6] = (_Float16)b.z; h[7] = (_Float16)b.w;
    *((half8*)wh + idx) = h;
}

// ---------------- fp16 MFMA GEMM, persistent 256x256 8-phase schedule ----------------
// Grid = 256 blocks (1/CU). Block b: n-tile = b&7 (== XCD -> 512KB B panel L2-resident),
// m-chunk = b>>3 -> 4 consecutive 256-row m-tiles, processed as ONE continuous
// 64-K-tile pipeline (global K-tile stream g = tile*16 + kt; LDS buffer = g&1).
// Per K-tile per wave: 64 MFMA in 4 phases of 16; iteration = 2 K-tiles = 8 phases.
//
// LDS swizzle (T2): byte kb within a 128B row XORed with (row&7)<<4 on BOTH sides
// (ds_read addr + pre-swizzled GLOBAL source; LDS dest linear — rule #21).
//
// Stage ledger (region's last ds_read >= 1 phase before its stage; seamless
// across m-tile boundaries because g-indexing is linear):
//   ph0: A(g=t+1, rows 64,192)   ph1: B(t+2, 0,64)   ph2: A(t+2, 0,128)
//   ph3: B(t+2, 128,192)         ph4: A(t+2, 64,192) ph5: B(t+3, 0,64)
//   ph6: A(t+3, 0,128)           ph7: B(t+3, 128,192)
// Waits: end ph3 vmcnt(6) (buf of t+1 complete; last iter vmcnt(0)),
//        end ph7 vmcnt(6) (buf of t+2 complete).
// Mid-stream epilogue after it%8==7: acc stores issued; following vmcnt(6)
// over-waits those stores once (stores are oldest in FIFO) — safe, ~100s of cyc.
#define BM 256
#define BN 256
#define BK 64
#define TPB 4              // m-tiles per block
#define NGT (TPB * 16)     // 64 global K-tiles
#define NIT (NGT / 2)      // 32 iterations

__global__ __launch_bounds__(512, 2) void gemm_f16_kernel(
    const _Float16* __restrict__ A, const _Float16* __restrict__ B,
    uint* __restrict__ zf) {
    __shared__ __attribute__((aligned(128))) _Float16 smem[65536];  // 128 KB
    char* smb = (char*)smem;

    const int tid  = threadIdx.x;
    const int lane = tid & 63;
    const int wv   = tid >> 6;               // wave 0..7
    const int wm_off = (wv >> 2) * 128;      // wave's 128-row A half
    const int wn_off = (wv & 3) * 64;        // wave's 64-row B quarter

    const int n0g  = (blockIdx.x & 7) * BN;          // n-tile == XCD
    const int m_bs = (blockIdx.x >> 3) * (TPB * BM); // 1024-row m-chunk base

    const int fr  = lane & 15;               // fragment row within 16
    const int fkb = (lane >> 4) * 16;        // fragment k-chunk byte offset

    // staging lane constants: lane covers LDS linear bytes (lane*16) of an 8-row slice;
    // source k-byte pre-swizzled: ((lane&7)^(lane>>3))<<4
    const int srow = lane >> 3;
    const int skb  = ((lane & 7) ^ srow) << 4;

    floatx4 acc[8][4] = {};

    // STAGE one 8KB sub-chunk (64 rows x 64 k) of K-tile g into LDS buffer g&1
    auto STAGE_A = [&](int g, int R0) {
        int kt = g & 15, mt = (g >> 4) & 3;
        int r = R0 + wv * 8 + srow;
        const _Float16* gp = A + (size_t)(m_bs + mt * BM + r) * KDIM + kt * BK + (skb >> 1);
        __builtin_amdgcn_global_load_lds(
            (const __attribute__((address_space(1))) void*)gp,
            (__attribute__((address_space(3))) void*)(smb + (g & 1) * 65536 + (R0 + wv * 8) * 128),
            16, 0, 0);
    };
    auto STAGE_B = [&](int g, int R0) {
        int kt = g & 15;
        int r = R0 + wv * 8 + srow;
        const _Float16* gp = B + (size_t)(n0g + r) * KDIM + kt * BK + (skb >> 1);
        __builtin_amdgcn_global_load_lds(
            (const __attribute__((address_space(1))) void*)gp,
            (__attribute__((address_space(3))) void*)(smb + (g & 1) * 65536 + 32768 + (R0 + wv * 8) * 128),
            16, 0, 0);
    };
    // swizzled ds_read_b128 of fragment at (row r, k-byte kb) from region base rb
    auto LD8 = [&](int rb, int r, int kb) -> half8 {
        return *(const half8*)(smb + rb + r * 128 + (kb ^ ((r & 7) << 4)));
    };

    // ---- prologue: K-tile 0 fully, K-tile 1 first 3 half-tiles ----
    STAGE_B(0, 0);   STAGE_B(0, 64);
    STAGE_A(0, 0);   STAGE_A(0, 128);
    STAGE_B(0, 128); STAGE_B(0, 192);
    STAGE_A(0, 64);  STAGE_A(0, 192);
    STAGE_B(1, 0);   STAGE_B(1, 64);
    STAGE_A(1, 0);   STAGE_A(1, 128);
    STAGE_B(1, 128); STAGE_B(1, 192);
    asm volatile("s_waitcnt vmcnt(6)" ::: "memory");  // all of K-tile 0 landed
    __builtin_amdgcn_s_barrier();
    asm volatile("" ::: "memory");

    half8 bfr[4][2];
    for (int it = 0; it < NIT; ++it) {
        const int  t    = 2 * it;
        const bool more = (it < NIT - 1);
        #pragma unroll
        for (int ph = 0; ph < 8; ++ph) {
            const int bb    = ph >> 2;           // buffer (t even -> buf0 first)
            const int p     = ph & 3;            // sub-phase within K-tile
            const int bbase = bb * 65536;

            // ds-read register subtile (B cached across the 4 phases of a K-tile)
            if (p == 0) {
                #pragma unroll
                for (int j = 0; j < 4; ++j)
                    #pragma unroll
                    for (int ks = 0; ks < 2; ++ks) {
                        int r = wn_off + j * 16 + fr;
                        bfr[j][ks] = LD8(bbase + 32768, r, ks * 64 + fkb);
                    }
            }
            half8 afr[2][2];
            #pragma unroll
            for (int ii = 0; ii < 2; ++ii)
                #pragma unroll
                for (int ks = 0; ks < 2; ++ks) {
                    int r = wm_off + (2 * p + ii) * 16 + fr;
                    afr[ii][ks] = LD8(bbase, r, ks * 64 + fkb);
                }

            // stage one half-tile per the ledger
            if (ph == 0) {
                STAGE_A(t + 1, 64);  STAGE_A(t + 1, 192);
            } else if (more) {
                if      (ph == 1) { STAGE_B(t + 2, 0);   STAGE_B(t + 2, 64);  }
                else if (ph == 2) { STAGE_A(t + 2, 0);   STAGE_A(t + 2, 128); }
                else if (ph == 3) { STAGE_B(t + 2, 128); STAGE_B(t + 2, 192); }
                else if (ph == 4) { STAGE_A(t + 2, 64);  STAGE_A(t + 2, 192); }
                else if (ph == 5) { STAGE_B(t + 3, 0);   STAGE_B(t + 3, 64);  }
                else if (ph == 6) { STAGE_A(t + 3, 0);   STAGE_A(t + 3, 128); }
                else              { STAGE_B(t + 3, 128); STAGE_B(t + 3, 192); }
            }

            __builtin_amdgcn_s_barrier();
            asm volatile("s_waitcnt lgkmcnt(0)" ::: "memory");
            __builtin_amdgcn_s_setprio(1);
            #pragma unroll
            for (int ks = 0; ks < 2; ++ks)
                #pragma unroll
                for (int ii = 0; ii < 2; ++ii)
                    #pragma unroll
                    for (int j = 0; j < 4; ++j)
                        acc[2 * p + ii][j] = __builtin_amdgcn_mfma_f32_16x16x32_f16(
                            afr[ii][ks], bfr[j][ks], acc[2 * p + ii][j], 0, 0, 0);
            __builtin_amdgcn_s_setprio(0);
            if (ph == 3) {
                if (more) asm volatile("s_waitcnt vmcnt(6)" ::: "memory");
                else      asm volatile("s_waitcnt vmcnt(0)" ::: "memory");
            } else if (ph == 7) {
                if (more) asm volatile("s_waitcnt vmcnt(6)" ::: "memory");
            }
            __builtin_amdgcn_s_barrier();
            asm volatile("" ::: "memory");
        }

        // ---- per-m-tile epilogue (after every 8 iterations = 16 K-tiles) ----
        // C/D layout col=lane&15, row=(lane>>4)*4+reg [m89/m91]; col-tile pair
        // (2p,2p+1) = (z,f) for h = ((n0g+wn_off)>>5 + p)*16 + ocol.
        if ((it & 7) == 7) {
            const int m0   = m_bs + (it >> 3) * BM;
            const int orow = (lane >> 4) * 4;
            const int ocol = lane & 15;
            const int gb   = (n0g + wn_off) >> 5;
            #pragma unroll
            for (int i = 0; i < 8; ++i)
                #pragma unroll
                for (int p2 = 0; p2 < 2; ++p2) {
                    int hh = (gb + p2) * 16 + ocol;
                    #pragma unroll
                    for (int r = 0; r < 4; ++r) {
                        int row = m0 + wm_off + i * 16 + orow + r;
                        half2v v;
                        v[0] = (_Float16)acc[i][2 * p2][r];       // z
                        v[1] = (_Float16)acc[i][2 * p2 + 1][r];   // f
                        *(half2v*)(zf + (size_t)row * HID + hh) = v;
                    }
                }
            #pragma unroll
            for (int i = 0; i < 8; ++i)
                #pragma unroll
                for (int j = 0; j < 4; ++j)
                    acc[i][j] = (floatx4)0.0f;
        }
    }
}

// ---------------- sequential scan over s, one thread per (b,h) ----------------
// Critical path per step: fma -> v_exp -> add -> rcp -> fma -> sub -> fma (7 deps).
// tanh(u) = 1 - 2/(e^{2u}+1) with e^{2u} = 2^(azt*c + zb);  sigmoid(v) =
// 1/(1 + 2^(aft*c + fb)).  log2e factors folded into per-h constants; data-side
// fma is off the chain.  Saturation is graceful: rcp(inf)=0 -> tanh=+1.
#define UNR 32
__device__ __forceinline__ float fast_exp2(float x) {
    float r;
    asm("v_exp_f32 %0, %1" : "=v"(r) : "v"(x));
    return r;
}
__global__ __launch_bounds__(64) void scan_kernel(
    const uint* __restrict__ zf, float* __restrict__ out,
    const float* __restrict__ state,
    const float* __restrict__ wvz, const float* __restrict__ wvf,
    const float* __restrict__ bz, const float* __restrict__ bfv) {
    const int t = blockIdx.x * 64 + threadIdx.x;   // 0..32767
    const int h = t & (HID - 1);
    const int stride = BSZ * HID;

    float cell = state[t];
    const float L2E = 1.44269504088896f;
    const float azt = 2.0f * L2E * wvz[h];
    const float czt = 2.0f * L2E * bz[h];
    const float aft = -L2E * wvf[h];
    const float cft = -L2E * bfv[h];

    const uint* p = zf + t;
    float* po = out + t;

    uint buf[UNR];
    #pragma unroll
    for (int u = 0; u < UNR; ++u) buf[u] = p[(size_t)u * stride];

    for (int s0 = 0; s0 < S_LEN; s0 += UNR) {
        uint nb[UNR];
        if (s0 + UNR < S_LEN) {
            #pragma unroll
            for (int u = 0; u < UNR; ++u)
                nb[u] = p[(size_t)(s0 + UNR + u) * stride];
        }
        #pragma unroll
        for (int u = 0; u < UNR; ++u) {
            half2v h2 = __builtin_bit_cast(half2v, buf[u]);
            float zb = fmaf((float)h2[0], 2.0f * L2E, czt);   // off-chain
            float fb = fmaf((float)h2[1], -L2E, cft);          // off-chain
            float ez = fast_exp2(fmaf(azt, cell, zb));         // e^{2u}
            float zp = fmaf(-2.0f, __builtin_amdgcn_rcpf(ez + 1.0f), 1.0f);  // tanh
            float ef = fast_exp2(fmaf(aft, cell, fb));         // e^{-v}
            float fp = __builtin_amdgcn_rcpf(ef + 1.0f);       // sigmoid
            cell = fmaf(cell - zp, fp, zp);                    // cell*fp + (1-fp)*zp
            po[(size_t)(s0 + u) * stride] = cell;
        }
        #pragma unroll
        for (int u = 0; u < UNR; ++u) buf[u] = nb[u];
    }
}

extern "C" void kernel_launch(void* const* d_in, const int* in_sizes, int n_in,
                              void* d_out, int out_size, void* d_ws, size_t ws_size,
                              hipStream_t stream) {
    const float* x      = (const float*)d_in[0];
    const float* state  = (const float*)d_in[1];
    const float* wm_z   = (const float*)d_in[2];
    const float* wm_f   = (const float*)d_in[3];
    const float* wv_z   = (const float*)d_in[4];
    const float* wv_f   = (const float*)d_in[5];
    const float* bias_z = (const float*)d_in[6];
    const float* bias_f = (const float*)d_in[7];
    float* out = (float*)d_out;

    // workspace layout: xh 64MB | wh 4MB | zf 128MB  (total 196MB)
    char* ws = (char*)d_ws;
    _Float16* xh = (_Float16*)ws;
    _Float16* wh = (_Float16*)(ws + (size_t)MDIM * KDIM * sizeof(_Float16));
    uint* zf     = (uint*)(ws + (size_t)MDIM * KDIM * sizeof(_Float16)
                              + (size_t)NDIM * KDIM * sizeof(_Float16));

    // 1) convert inputs to fp16 (weights interleaved z|f in 16-row groups)
    cvt_x_kernel<<<(MDIM * KDIM) / (256 * 8), 256, 0, stream>>>(x, xh);
    cvt_w_kernel<<<(NDIM * KDIM) / (256 * 8), 256, 0, stream>>>(wm_z, wm_f, wh);

    // 2) persistent fused z|f projection GEMM -> interleaved fp16 pre-activations
    gemm_f16_kernel<<<256, 512, 0, stream>>>(xh, wh, zf);

    // 3) recurrence -> fp32 output
    scan_kernel<<<MDIM / 64, 64, 0, stream>>>(zf, out, state, wv_z, wv_f, bias_z, bias_f);
}